// Round 12
// baseline (162.042 us; speedup 1.0000x reference)
//
#include <hip/hip_runtime.h>
#include <hip/hip_bf16.h>
#include <math.h>

#define NN 8192
#define DD 128
#define BIGF 3.402823466e+38f

typedef __attribute__((ext_vector_type(8))) short short8;
typedef __attribute__((ext_vector_type(4))) float f32x4;

static __device__ __forceinline__ unsigned short bfc(float f) {
    return __bfloat16_as_ushort(__float2bfloat16(f));
}
static __device__ __forceinline__ short8 pk8(float4 a, float4 b) {
    short8 s;
    s[0] = (short)bfc(a.x); s[1] = (short)bfc(a.y);
    s[2] = (short)bfc(a.z); s[3] = (short)bfc(a.w);
    s[4] = (short)bfc(b.x); s[5] = (short)bfc(b.y);
    s[6] = (short)bfc(b.z); s[7] = (short)bfc(b.w);
    return s;
}
static __device__ __forceinline__ float sq4(float4 v) {
    return v.x * v.x + v.y * v.y + v.z * v.z + v.w * v.w;
}

// ---------------- fused: fp32 staging + bf16 convert + norms + MFMA + reduce ----------------
// loss = 1 - 1/8192 + T/(N*M) - (P_r + P_c)/16384 (hinge never clips: d >= pos).
// Mins tracked on d^2 (sqrt monotone). 128x128 tile, 4 waves (2x2), 64x64/wave.
// prep is FUSED: each block stages its own panels from fp32, converting to bf16
// on the LDS write and accumulating fp32 row norms in-kernel (8 threads/row
// shfl-tree -> LDS nrm[128]). Conversion is 64x redundant but deletes a whole
// dispatch (~4us overhead) + prep work + the bf16 intermediate round-trip.
// (256,3): ~170 unified regs -> no spill with fp32 staging temps (R11 sat at the
// exact 64V+64A cap of (256,4), throttling ILP). LDS 35.9KB still fits 4 blocks.
// Zero atomics in the hot path (R10 lesson); bijective XCD swizzle (R11).
__global__ __launch_bounds__(256, 3) void dist_fused(
    const float* __restrict__ A32, const float* __restrict__ B32,
    float* __restrict__ rowpart, float* __restrict__ colpart,
    float* __restrict__ totpart, unsigned int* __restrict__ done) {
    __shared__ char lds[32768];
    __shared__ float nrmA[128], nrmB[128];
    __shared__ float rmbuf[2][128];   // [wc][row_in_block]
    __shared__ float cmbuf[2][128];   // [wr][col_in_block]
    __shared__ float tbuf[4];
    char* ldsA = lds;
    char* ldsB = lds + 16384;
    const int tid = threadIdx.x;

    if (blockIdx.x == 0 && blockIdx.y == 0 && tid == 0) *done = 0u;  // replay-safe

    // bijective XCD swizzle (4096 blocks, 8 XCDs)
    const int lin = blockIdx.y * 64 + blockIdx.x;
    const int swz = (lin & 7) * 512 + (lin >> 3);
    const int bx = swz & 63, by = swz >> 6;
    const int rowBase = by * 128;
    const int colBase = bx * 128;

    const float* aG = A32 + (size_t)rowBase * DD;
    const float* bG = B32 + (size_t)colBase * DD;

    const int l = tid & 63, wid = tid >> 6;
    const int wr = wid >> 1, wc = wid & 1;   // wave 64x64 sub-tile
    const int g = l >> 4, c = l & 15;

    f32x4 acc[4][4];
#pragma unroll
    for (int mi = 0; mi < 4; ++mi)
#pragma unroll
        for (int ni = 0; ni < 4; ++ni) acc[mi][ni] = (f32x4)0.f;

    float ssA[4] = {0.f, 0.f, 0.f, 0.f};   // per-it row sumsq partials
    float ssB[4] = {0.f, 0.f, 0.f, 0.f};

#pragma unroll
    for (int p = 0; p < 2; ++p) {
        if (p) __syncthreads();   // previous compute done before overwrite
        // stage 128 rows x 64 cols from fp32, convert to bf16, XOR-swizzled LDS
#pragma unroll
        for (int it = 0; it < 4; ++it) {
            int idx = tid + 256 * it;   // 0..1023
            int r = idx >> 3;           // row 0..127
            int c16 = idx & 7;          // 8-elem chunk in the 64-col phase
            const float* pa = aG + r * DD + p * 64 + c16 * 8;
            const float* pb = bG + r * DD + p * 64 + c16 * 8;
            float4 va0 = *(const float4*)pa, va1 = *(const float4*)(pa + 4);
            float4 vb0 = *(const float4*)pb, vb1 = *(const float4*)(pb + 4);
            ssA[it] += sq4(va0) + sq4(va1);
            ssB[it] += sq4(vb0) + sq4(vb1);
            int dst = r * 128 + ((c16 * 16) ^ ((r & 7) << 4));
            *(short8*)(ldsA + dst) = pk8(va0, va1);
            *(short8*)(ldsB + dst) = pk8(vb0, vb1);
        }
        if (p == 1) {
            // fold per-thread sumsq into per-row norms (8 threads own a row)
#pragma unroll
            for (int it = 0; it < 4; ++it) {
                int r = (tid + 256 * it) >> 3;
                float sa = ssA[it];
                sa += __shfl_xor(sa, 1, 64);
                sa += __shfl_xor(sa, 2, 64);
                sa += __shfl_xor(sa, 4, 64);
                float sb = ssB[it];
                sb += __shfl_xor(sb, 1, 64);
                sb += __shfl_xor(sb, 2, 64);
                sb += __shfl_xor(sb, 4, 64);
                if ((tid & 7) == 0) { nrmA[r] = sa; nrmB[r] = sb; }
            }
        }
        __syncthreads();
#pragma unroll
        for (int kk = 0; kk < 2; ++kk) {
            short8 af[4], bf[4];
            const int kbyte = kk * 64 + g * 16;
#pragma unroll
            for (int mi = 0; mi < 4; ++mi) {
                int r = wr * 64 + mi * 16 + c;
                af[mi] = *(const short8*)(ldsA + r * 128 + (kbyte ^ ((r & 7) << 4)));
                int r2 = wc * 64 + mi * 16 + c;
                bf[mi] = *(const short8*)(ldsB + r2 * 128 + (kbyte ^ ((r2 & 7) << 4)));
            }
#pragma unroll
            for (int mi = 0; mi < 4; ++mi)
#pragma unroll
                for (int ni = 0; ni < 4; ++ni)
                    acc[mi][ni] = __builtin_amdgcn_mfma_f32_16x16x32_bf16(
                        af[mi], bf[ni], acc[mi][ni], 0, 0, 0);
        }
    }

    // out_row = row0 + mi*16 + g*4 + reg ; out_col = col0 + ni*16 + c
    const int row0 = rowBase + wr * 64;
    const int col0 = colBase + wc * 64;

    float nbc[4];
#pragma unroll
    for (int ni = 0; ni < 4; ++ni) nbc[ni] = nrmB[wc * 64 + ni * 16 + c];

    float colm2[4] = {BIGF, BIGF, BIGF, BIGF};
    f32x4 tot4 = (f32x4)0.f;
#pragma unroll
    for (int mi = 0; mi < 4; ++mi) {
        const f32x4 na4 = *(const f32x4*)&nrmA[wr * 64 + mi * 16 + g * 4];
        float rowm2[4] = {BIGF, BIGF, BIGF, BIGF};
#pragma unroll
        for (int ni = 0; ni < 4; ++ni) {
            f32x4 a = acc[mi][ni];
#pragma unroll
            for (int reg = 0; reg < 4; ++reg) {
                float d2 = fmaf(-2.0f, a[reg], na4[reg] + nbc[ni]);
                rowm2[reg] = fminf(rowm2[reg], d2);
                colm2[ni] = fminf(colm2[ni], d2);
                tot4[reg] += __builtin_amdgcn_sqrtf(fmaxf(d2, 0.f));
            }
        }
        // row d^2 mins: reduce across the 16 c-lanes
#pragma unroll
        for (int reg = 0; reg < 4; ++reg) {
            float m = rowm2[reg];
            m = fminf(m, __shfl_xor(m, 1, 64));
            m = fminf(m, __shfl_xor(m, 2, 64));
            m = fminf(m, __shfl_xor(m, 4, 64));
            m = fminf(m, __shfl_xor(m, 8, 64));
            if (c == 0) rmbuf[wc][wr * 64 + mi * 16 + g * 4 + reg] = m;
        }
    }
    // col d^2 mins: reduce across the 4 g-groups
#pragma unroll
    for (int ni = 0; ni < 4; ++ni) {
        float m = colm2[ni];
        m = fminf(m, __shfl_xor(m, 16, 64));
        m = fminf(m, __shfl_xor(m, 32, 64));
        if (g == 0) cmbuf[wr][wc * 64 + ni * 16 + c] = m;
    }
    // grand total: wave reduce
    float tot = (tot4[0] + tot4[1]) + (tot4[2] + tot4[3]);
#pragma unroll
    for (int off = 32; off >= 1; off >>= 1) tot += __shfl_xor(tot, off, 64);
    if (l == 0) tbuf[wid] = tot;
    __syncthreads();

    // plain disjoint stores - no atomics anywhere in the hot path
    if (tid < 128) {
        rowpart[(size_t)bx * NN + rowBase + tid] = fminf(rmbuf[0][tid], rmbuf[1][tid]);
    } else if (tid < 256) {
        int j = tid - 128;
        colpart[(size_t)by * NN + colBase + j] = fminf(cmbuf[0][j], cmbuf[1][j]);
    }
    if (tid == 0)
        totpart[by * 64 + bx] = tbuf[0] + tbuf[1] + tbuf[2] + tbuf[3];
}

// ---------------- fin: 64-way partial reduce + last-block scalar emit ----------------
__global__ __launch_bounds__(256) void fin_kernel(const float* __restrict__ rowpart,
                                                  const float* __restrict__ colpart,
                                                  const float* __restrict__ totpart,
                                                  float* __restrict__ finpart,
                                                  unsigned int* __restrict__ done,
                                                  float* __restrict__ out) {
    const int idx = blockIdx.x * 256 + threadIdx.x;   // 0..16383
    const int j = (idx < NN) ? idx : idx - NN;
    const float* p = (idx < NN) ? rowpart : colpart;
    float m = BIGF;
#pragma unroll 8
    for (int k = 0; k < 64; ++k) m = fminf(m, p[(size_t)k * NN + j]);
    float contrib = -__builtin_amdgcn_sqrtf(fmaxf(m, 0.f)) * (1.0f / 16384.0f);
    if (blockIdx.x < 16)
        contrib += totpart[blockIdx.x * 256 + threadIdx.x] * (1.0f / 67108864.0f);
#pragma unroll
    for (int off = 32; off >= 1; off >>= 1) contrib += __shfl_xor(contrib, off, 64);
    __shared__ float red[4];
    __shared__ unsigned last;
    if ((threadIdx.x & 63) == 0) red[threadIdx.x >> 6] = contrib;
    __syncthreads();
    if (threadIdx.x == 0) {
        finpart[blockIdx.x] = red[0] + red[1] + red[2] + red[3];
        __threadfence();                       // release finpart
        last = (atomicAdd(done, 1u) == 63u) ? 1u : 0u;
    }
    __syncthreads();
    if (last && threadIdx.x < 64) {
        __threadfence();                       // acquire
        float s = __hip_atomic_load(&finpart[threadIdx.x], __ATOMIC_RELAXED,
                                    __HIP_MEMORY_SCOPE_AGENT);
#pragma unroll
        for (int off = 32; off >= 1; off >>= 1) s += __shfl_xor(s, off, 64);
        if (threadIdx.x == 0) out[0] = s + 1.0f - 1.0f / 8192.0f;
    }
}

extern "C" void kernel_launch(void* const* d_in, const int* in_sizes, int n_in,
                              void* d_out, int out_size, void* d_ws, size_t ws_size,
                              hipStream_t stream) {
    const float* A = (const float*)d_in[0];
    const float* B = (const float*)d_in[1];
    char* ws = (char*)d_ws;

    const size_t MB = 1024 * 1024;
    float* rowpart = (float*)(ws);                       // 2 MB  [ct][8192]
    float* colpart = (float*)(ws + 2 * MB);              // 2 MB  [rt][8192]
    float* totpart = (float*)(ws + 4 * MB);              // 16 KB
    float* finpart = (float*)(ws + 4 * MB + 16384);      // 256 B
    unsigned int* done = (unsigned int*)(ws + 4 * MB + 16384 + 256);

    dim3 grid(NN / 128, NN / 128);
    dist_fused<<<grid, 256, 0, stream>>>(A, B, rowpart, colpart, totpart, done);

    fin_kernel<<<64, 256, 0, stream>>>(rowpart, colpart, totpart, finpart, done,
                                       (float*)d_out);
}

// Round 13
// 67.691 us; speedup vs baseline: 2.3938x; 2.3938x over previous
//
#include <hip/hip_runtime.h>
#include <hip/hip_bf16.h>
#include <math.h>

#define NN 8192
#define DD 128
#define BIGF 3.402823466e+38f

typedef __attribute__((ext_vector_type(8))) short short8;
typedef __attribute__((ext_vector_type(4))) float f32x4;

static __device__ __forceinline__ unsigned short bfc(float f) {
    return __bfloat16_as_ushort(__float2bfloat16(f));
}

// ---------------- prep: fp32 -> bf16 + exact fp32 row norms + done init ----------------
// (R12 lesson: bf16 intermediate is what makes dist's panel re-reads L2-resident;
// staging dist from fp32 = 512 MB logical traffic, blows per-XCD L2.)
__global__ __launch_bounds__(256) void prep_kernel(const float* __restrict__ A,
                                                   const float* __restrict__ B,
                                                   __hip_bfloat16* __restrict__ Abf,
                                                   __hip_bfloat16* __restrict__ Bbf,
                                                   float* __restrict__ na,
                                                   float* __restrict__ nb,
                                                   unsigned int* __restrict__ done) {
    if (blockIdx.y == 0 && blockIdx.x == 0 && threadIdx.x == 0) *done = 0u;
    const float* x = blockIdx.y ? B : A;
    __hip_bfloat16* xb = blockIdx.y ? Bbf : Abf;
    float* norm = blockIdx.y ? nb : na;
    const int sub = threadIdx.x >> 5;
    const int ch  = threadIdx.x & 31;
    const int row = blockIdx.x * 8 + sub;
    const float4 v = *(const float4*)(x + (size_t)row * DD + ch * 4);
    float s = v.x * v.x + v.y * v.y + v.z * v.z + v.w * v.w;
    uint2 pk;
    pk.x = ((unsigned)bfc(v.y) << 16) | bfc(v.x);
    pk.y = ((unsigned)bfc(v.w) << 16) | bfc(v.z);
    *(uint2*)(xb + (size_t)row * DD + ch * 4) = pk;
#pragma unroll
    for (int off = 16; off >= 1; off >>= 1) s += __shfl_xor(s, off, 64);
    if (ch == 0) norm[row] = s;
}

// ---------------- fused MFMA distance pass: 256x128 tile, 8 waves, T14 prefetch ----------------
// loss = 1 - 1/8192 + T/(N*M) - (P_r + P_c)/16384 (hinge never clips: d >= pos).
// Mins on d^2 (sqrt monotone). 8 waves (4 row x 2 col groups), 64x64 per wave.
// K in two 64-wide phases; LDS A 32KB + B 16KB. Phase-1 global loads are issued
// into registers BEFORE phase-0's barrier+MFMA (T14 async-STAGE: L2 latency hides
// under compute). Half the blocks of the 128x128 version -> half the per-CU
// barrier-drain + epilogue events. Zero atomics (R10); bijective XCD swizzle
// (2048 blocks, chunk 256/XCD: A 8x64KB-bf16 + B 2MB-bf16 fits 4MB L2).
__global__ __launch_bounds__(512, 4) void dist_fused(
    const __hip_bfloat16* __restrict__ Ab, const __hip_bfloat16* __restrict__ Bb,
    const float* __restrict__ na, const float* __restrict__ nb,
    float* __restrict__ rowpart, float* __restrict__ colpart,
    float* __restrict__ totpart) {
    __shared__ char lds[49152];
    __shared__ float rmbuf[2][256];   // [wc][row_in_block]
    __shared__ float cmbuf[4][128];   // [wr][col_in_block]
    __shared__ float tbuf[8];
    char* ldsA = lds;
    char* ldsB = lds + 32768;
    const int tid = threadIdx.x;
    const int l = tid & 63, wid = tid >> 6;
    const int wr = wid >> 1, wc = wid & 1;   // 4x2 wave grid, 64x64 each
    const int g = l >> 4, c = l & 15;

    // bijective XCD swizzle (2048 blocks, 8 XCDs, 256 blocks/XCD chunk)
    const int lin = blockIdx.y * 64 + blockIdx.x;
    const int swz = (lin & 7) * 256 + (lin >> 3);
    const int bx = swz & 63, by = swz >> 6;   // bx: col panel (128), by: row panel (256)
    const int rowBase = by * 256;
    const int colBase = bx * 128;

    const unsigned short* aG = (const unsigned short*)Ab + (size_t)rowBase * DD;
    const unsigned short* bG = (const unsigned short*)Bb + (size_t)colBase * DD;

    f32x4 acc[4][4];
#pragma unroll
    for (int mi = 0; mi < 4; ++mi)
#pragma unroll
        for (int ni = 0; ni < 4; ++ni) acc[mi][ni] = (f32x4)0.f;

    // ---- phase-0 load -> LDS write; phase-1 load issued EARLY (T14) ----
    short8 sa[4], sb[2], ta[4], tb[2];
#pragma unroll
    for (int it = 0; it < 4; ++it) {
        int idx = tid + 512 * it;   // A: 2048 chunks (256 rows x 8)
        sa[it] = *(const short8*)(aG + (idx >> 3) * DD + (idx & 7) * 8);
    }
#pragma unroll
    for (int it = 0; it < 2; ++it) {
        int idx = tid + 512 * it;   // B: 1024 chunks (128 rows x 8)
        sb[it] = *(const short8*)(bG + (idx >> 3) * DD + (idx & 7) * 8);
    }
#pragma unroll
    for (int it = 0; it < 4; ++it) {
        int idx = tid + 512 * it, r = idx >> 3, c16 = idx & 7;
        *(short8*)(ldsA + r * 128 + ((c16 * 16) ^ ((r & 7) << 4))) = sa[it];
    }
#pragma unroll
    for (int it = 0; it < 2; ++it) {
        int idx = tid + 512 * it, r = idx >> 3, c16 = idx & 7;
        *(short8*)(ldsB + r * 128 + ((c16 * 16) ^ ((r & 7) << 4))) = sb[it];
    }
#pragma unroll
    for (int it = 0; it < 4; ++it) {
        int idx = tid + 512 * it;
        ta[it] = *(const short8*)(aG + (idx >> 3) * DD + 64 + (idx & 7) * 8);
    }
#pragma unroll
    for (int it = 0; it < 2; ++it) {
        int idx = tid + 512 * it;
        tb[it] = *(const short8*)(bG + (idx >> 3) * DD + 64 + (idx & 7) * 8);
    }
    __syncthreads();

#define COMPUTE_PHASE() do {                                                      \
    _Pragma("unroll")                                                             \
    for (int kk = 0; kk < 2; ++kk) {                                              \
        short8 af[4], bf[4];                                                      \
        const int kbyte = kk * 64 + g * 16;                                       \
        _Pragma("unroll")                                                         \
        for (int mi = 0; mi < 4; ++mi) {                                          \
            int r = wr * 64 + mi * 16 + c;                                        \
            af[mi] = *(const short8*)(ldsA + r * 128 + (kbyte ^ ((r & 7) << 4))); \
            int r2 = wc * 64 + mi * 16 + c;                                       \
            bf[mi] = *(const short8*)(ldsB + r2 * 128 + (kbyte ^ ((r2 & 7) << 4)));\
        }                                                                         \
        _Pragma("unroll")                                                         \
        for (int mi = 0; mi < 4; ++mi)                                            \
            _Pragma("unroll")                                                     \
            for (int ni = 0; ni < 4; ++ni)                                        \
                acc[mi][ni] = __builtin_amdgcn_mfma_f32_16x16x32_bf16(            \
                    af[mi], bf[ni], acc[mi][ni], 0, 0, 0);                        \
    } } while (0)

    COMPUTE_PHASE();      // phase 0 (ta/tb loads in flight underneath)
    __syncthreads();      // all waves done reading phase-0 LDS
#pragma unroll
    for (int it = 0; it < 4; ++it) {
        int idx = tid + 512 * it, r = idx >> 3, c16 = idx & 7;
        *(short8*)(ldsA + r * 128 + ((c16 * 16) ^ ((r & 7) << 4))) = ta[it];
    }
#pragma unroll
    for (int it = 0; it < 2; ++it) {
        int idx = tid + 512 * it, r = idx >> 3, c16 = idx & 7;
        *(short8*)(ldsB + r * 128 + ((c16 * 16) ^ ((r & 7) << 4))) = tb[it];
    }
    __syncthreads();
    COMPUTE_PHASE();      // phase 1
#undef COMPUTE_PHASE

    // out_row = rowBase + wr*64 + mi*16 + g*4 + reg ; out_col = colBase + wc*64 + ni*16 + c
    const int row0 = rowBase + wr * 64;
    const int col0 = colBase + wc * 64;

    float nbc[4];
#pragma unroll
    for (int ni = 0; ni < 4; ++ni) nbc[ni] = nb[col0 + ni * 16 + c];

    float colm2[4] = {BIGF, BIGF, BIGF, BIGF};
    f32x4 tot4 = (f32x4)0.f;
#pragma unroll
    for (int mi = 0; mi < 4; ++mi) {
        const f32x4 na4 = *(const f32x4*)(na + row0 + mi * 16 + g * 4);
        float rowm2[4] = {BIGF, BIGF, BIGF, BIGF};
#pragma unroll
        for (int ni = 0; ni < 4; ++ni) {
            f32x4 a = acc[mi][ni];
#pragma unroll
            for (int reg = 0; reg < 4; ++reg) {
                float d2 = fmaf(-2.0f, a[reg], na4[reg] + nbc[ni]);
                rowm2[reg] = fminf(rowm2[reg], d2);
                colm2[ni] = fminf(colm2[ni], d2);
                tot4[reg] += __builtin_amdgcn_sqrtf(fmaxf(d2, 0.f));
            }
        }
#pragma unroll
        for (int reg = 0; reg < 4; ++reg) {
            float m = rowm2[reg];
            m = fminf(m, __shfl_xor(m, 1, 64));
            m = fminf(m, __shfl_xor(m, 2, 64));
            m = fminf(m, __shfl_xor(m, 4, 64));
            m = fminf(m, __shfl_xor(m, 8, 64));
            if (c == 0) rmbuf[wc][wr * 64 + mi * 16 + g * 4 + reg] = m;
        }
    }
#pragma unroll
    for (int ni = 0; ni < 4; ++ni) {
        float m = colm2[ni];
        m = fminf(m, __shfl_xor(m, 16, 64));
        m = fminf(m, __shfl_xor(m, 32, 64));
        if (g == 0) cmbuf[wr][wc * 64 + ni * 16 + c] = m;
    }
    float tot = (tot4[0] + tot4[1]) + (tot4[2] + tot4[3]);
#pragma unroll
    for (int off = 32; off >= 1; off >>= 1) tot += __shfl_xor(tot, off, 64);
    if (l == 0) tbuf[wid] = tot;
    __syncthreads();

    // plain disjoint stores - no atomics
    if (tid < 256) {
        rowpart[(size_t)bx * NN + rowBase + tid] = fminf(rmbuf[0][tid], rmbuf[1][tid]);
    } else if (tid < 384) {
        int j = tid - 256;
        colpart[(size_t)by * NN + colBase + j] =
            fminf(fminf(cmbuf[0][j], cmbuf[1][j]), fminf(cmbuf[2][j], cmbuf[3][j]));
    } else if (tid == 384) {
        float s = 0.f;
#pragma unroll
        for (int w = 0; w < 8; ++w) s += tbuf[w];
        totpart[by * 64 + bx] = s;
    }
}

// ---------------- fin: partial reduce + last-block scalar emit ----------------
__global__ __launch_bounds__(256) void fin_kernel(const float* __restrict__ rowpart,
                                                  const float* __restrict__ colpart,
                                                  const float* __restrict__ totpart,
                                                  float* __restrict__ finpart,
                                                  unsigned int* __restrict__ done,
                                                  float* __restrict__ out) {
    const int idx = blockIdx.x * 256 + threadIdx.x;   // 0..16383
    float m = BIGF;
    if (idx < NN) {
#pragma unroll 8
        for (int k = 0; k < 64; ++k) m = fminf(m, rowpart[(size_t)k * NN + idx]);
    } else {
        const int j = idx - NN;
#pragma unroll 8
        for (int k = 0; k < 32; ++k) m = fminf(m, colpart[(size_t)k * NN + j]);
    }
    float contrib = -__builtin_amdgcn_sqrtf(fmaxf(m, 0.f)) * (1.0f / 16384.0f);
    if (blockIdx.x < 8)
        contrib += totpart[blockIdx.x * 256 + threadIdx.x] * (1.0f / 67108864.0f);
#pragma unroll
    for (int off = 32; off >= 1; off >>= 1) contrib += __shfl_xor(contrib, off, 64);
    __shared__ float red[4];
    __shared__ unsigned last;
    if ((threadIdx.x & 63) == 0) red[threadIdx.x >> 6] = contrib;
    __syncthreads();
    if (threadIdx.x == 0) {
        finpart[blockIdx.x] = red[0] + red[1] + red[2] + red[3];
        __threadfence();                       // release finpart
        last = (atomicAdd(done, 1u) == 63u) ? 1u : 0u;
    }
    __syncthreads();
    if (last && threadIdx.x < 64) {
        __threadfence();                       // acquire
        float s = __hip_atomic_load(&finpart[threadIdx.x], __ATOMIC_RELAXED,
                                    __HIP_MEMORY_SCOPE_AGENT);
#pragma unroll
        for (int off = 32; off >= 1; off >>= 1) s += __shfl_xor(s, off, 64);
        if (threadIdx.x == 0) out[0] = s + 1.0f - 1.0f / 8192.0f;
    }
}

extern "C" void kernel_launch(void* const* d_in, const int* in_sizes, int n_in,
                              void* d_out, int out_size, void* d_ws, size_t ws_size,
                              hipStream_t stream) {
    const float* A = (const float*)d_in[0];
    const float* B = (const float*)d_in[1];
    char* ws = (char*)d_ws;

    const size_t MB = 1024 * 1024;
    __hip_bfloat16* Abf = (__hip_bfloat16*)(ws);                  // 2 MB
    __hip_bfloat16* Bbf = (__hip_bfloat16*)(ws + 2 * MB);         // 2 MB
    float* na      = (float*)(ws + 4 * MB);                       // 32 KB
    float* nb      = (float*)(ws + 4 * MB + 32768);               // 32 KB
    float* rowpart = (float*)(ws + 4 * MB + 65536);               // 2 MB  [64][8192]
    float* colpart = (float*)(ws + 6 * MB + 65536);               // 1 MB  [32][8192]
    float* totpart = (float*)(ws + 7 * MB + 65536);               // 8 KB  [2048]
    float* finpart = (float*)(ws + 7 * MB + 65536 + 8192);        // 256 B
    unsigned int* done = (unsigned int*)(ws + 7 * MB + 65536 + 8192 + 256);

    dim3 pgrid(NN / 8, 2);
    prep_kernel<<<pgrid, 256, 0, stream>>>(A, B, Abf, Bbf, na, nb, done);

    dim3 grid(64, 32);   // 64 col-panels x 32 row-panels
    dist_fused<<<grid, 512, 0, stream>>>(Abf, Bbf, na, nb, rowpart, colpart, totpart);

    fin_kernel<<<64, 256, 0, stream>>>(rowpart, colpart, totpart, finpart, done,
                                       (float*)d_out);
}

// Round 14
// 67.666 us; speedup vs baseline: 2.3947x; 1.0004x over previous
//
#include <hip/hip_runtime.h>
#include <hip/hip_bf16.h>
#include <math.h>

#define NN 8192
#define DD 128
#define BIGF 3.402823466e+38f

typedef __attribute__((ext_vector_type(8))) short short8;
typedef __attribute__((ext_vector_type(4))) float f32x4;

static __device__ __forceinline__ unsigned short bfc(float f) {
    return __bfloat16_as_ushort(__float2bfloat16(f));
}

// ---------------- prep: fp32 -> bf16 + exact fp32 row norms + done init ----------------
// (R12 lesson: the bf16 intermediate is what makes dist's panel re-reads L2-resident.)
__global__ __launch_bounds__(256) void prep_kernel(const float* __restrict__ A,
                                                   const float* __restrict__ B,
                                                   __hip_bfloat16* __restrict__ Abf,
                                                   __hip_bfloat16* __restrict__ Bbf,
                                                   float* __restrict__ na,
                                                   float* __restrict__ nb,
                                                   unsigned int* __restrict__ done) {
    if (blockIdx.y == 0 && blockIdx.x == 0 && threadIdx.x == 0) *done = 0u;
    const float* x = blockIdx.y ? B : A;
    __hip_bfloat16* xb = blockIdx.y ? Bbf : Abf;
    float* norm = blockIdx.y ? nb : na;
    const int sub = threadIdx.x >> 5;
    const int ch  = threadIdx.x & 31;
    const int row = blockIdx.x * 8 + sub;
    const float4 v = *(const float4*)(x + (size_t)row * DD + ch * 4);
    float s = v.x * v.x + v.y * v.y + v.z * v.z + v.w * v.w;
    uint2 pk;
    pk.x = ((unsigned)bfc(v.y) << 16) | bfc(v.x);
    pk.y = ((unsigned)bfc(v.w) << 16) | bfc(v.z);
    *(uint2*)(xb + (size_t)row * DD + ch * 4) = pk;
#pragma unroll
    for (int off = 16; off >= 1; off >>= 1) s += __shfl_xor(s, off, 64);
    if (ch == 0) norm[row] = s;
}

// ---------------- fused MFMA distance pass (R11 base + lean epilogue) ----------------
// loss = 1 - 1/8192 + T/(N*M) - (P_r + P_c)/16384 (hinge never clips: d >= pos).
// Mins tracked on d^2 (sqrt monotone). 128x128 tile, 4 waves (2x2), 64x64/wave.
// K in two 64-wide phases -> 32 KB tile LDS. Zero atomics (R10); bijective XCD
// swizzle (R11). Epilogue R14: per-mi dv[4][4] register block reduced with
// fminf-nesting that fuses to v_min3 (T17); row-min shuffle tree cut to 2 levels
// with 4 partials/row in LDS folded at the store stage (halves shfl+fmin count).
// (256,3): ~170-reg cap so dv[] fits without spill (R11 sat at exactly 64).
__global__ __launch_bounds__(256, 3) void dist_fused(
    const __hip_bfloat16* __restrict__ Ab, const __hip_bfloat16* __restrict__ Bb,
    const float* __restrict__ na, const float* __restrict__ nb,
    float* __restrict__ rowpart, float* __restrict__ colpart,
    float* __restrict__ totpart) {
    __shared__ char lds[32768];
    __shared__ float rmbuf[2][128][4];   // [wc][row_in_block][c-group partial]
    __shared__ float cmbuf[2][128];      // [wr][col_in_block]
    __shared__ float tbuf[4];
    char* ldsA = lds;
    char* ldsB = lds + 16384;
    const int tid = threadIdx.x;

    // bijective XCD swizzle (4096 blocks, 8 XCDs)
    const int lin = blockIdx.y * 64 + blockIdx.x;
    const int swz = (lin & 7) * 512 + (lin >> 3);
    const int bx = swz & 63, by = swz >> 6;
    const int rowBase = by * 128;
    const int colBase = bx * 128;

    const unsigned short* aG = (const unsigned short*)Ab + (size_t)rowBase * DD;
    const unsigned short* bG = (const unsigned short*)Bb + (size_t)colBase * DD;

    const int l = tid & 63, wid = tid >> 6;
    const int wr = wid >> 1, wc = wid & 1;   // wave 64x64 sub-tile
    const int g = l >> 4, c = l & 15;

    f32x4 acc[4][4];
#pragma unroll
    for (int mi = 0; mi < 4; ++mi)
#pragma unroll
        for (int ni = 0; ni < 4; ++ni) acc[mi][ni] = (f32x4)0.f;

#pragma unroll
    for (int p = 0; p < 2; ++p) {
        if (p) __syncthreads();   // previous compute done before overwrite
        // stage 128 rows x 64 bf16 (128 B/row) of A and B, XOR-swizzled
#pragma unroll
        for (int it = 0; it < 4; ++it) {
            int idx = tid + 256 * it;   // 0..1023
            int r = idx >> 3;           // row 0..127
            int c16 = idx & 7;          // 16B chunk in row
            int dst = r * 128 + ((c16 * 16) ^ ((r & 7) << 4));
            *(short8*)(ldsA + dst) = *(const short8*)(aG + r * DD + p * 64 + c16 * 8);
            *(short8*)(ldsB + dst) = *(const short8*)(bG + r * DD + p * 64 + c16 * 8);
        }
        __syncthreads();
#pragma unroll
        for (int kk = 0; kk < 2; ++kk) {
            short8 af[4], bf[4];
            const int kbyte = kk * 64 + g * 16;
#pragma unroll
            for (int mi = 0; mi < 4; ++mi) {
                int r = wr * 64 + mi * 16 + c;
                af[mi] = *(const short8*)(ldsA + r * 128 + (kbyte ^ ((r & 7) << 4)));
                int r2 = wc * 64 + mi * 16 + c;
                bf[mi] = *(const short8*)(ldsB + r2 * 128 + (kbyte ^ ((r2 & 7) << 4)));
            }
#pragma unroll
            for (int mi = 0; mi < 4; ++mi)
#pragma unroll
                for (int ni = 0; ni < 4; ++ni)
                    acc[mi][ni] = __builtin_amdgcn_mfma_f32_16x16x32_bf16(
                        af[mi], bf[ni], acc[mi][ni], 0, 0, 0);
        }
    }

    // out_row = row0 + mi*16 + g*4 + reg ; out_col = col0 + ni*16 + c
    const int row0 = rowBase + wr * 64;
    const int col0 = colBase + wc * 64;

    float nbc[4];
#pragma unroll
    for (int ni = 0; ni < 4; ++ni) nbc[ni] = nb[col0 + ni * 16 + c];

    float colm2[4] = {BIGF, BIGF, BIGF, BIGF};
    f32x4 tot4 = (f32x4)0.f;
#pragma unroll
    for (int mi = 0; mi < 4; ++mi) {
        const f32x4 na4 = *(const f32x4*)(na + row0 + mi * 16 + g * 4);
        float dv[4][4];   // [ni][reg] d^2 block, reduced via min3-fused trees
#pragma unroll
        for (int ni = 0; ni < 4; ++ni) {
            f32x4 a = acc[mi][ni];
#pragma unroll
            for (int reg = 0; reg < 4; ++reg) {
                float d2 = fmaf(-2.0f, a[reg], na4[reg] + nbc[ni]);
                dv[ni][reg] = d2;
                tot4[reg] += __builtin_amdgcn_sqrtf(fmaxf(d2, 0.f));
            }
            // nested fminf chain -> v_min3 x2
            colm2[ni] = fminf(fminf(fminf(fminf(colm2[ni], dv[ni][0]), dv[ni][1]),
                                    dv[ni][2]), dv[ni][3]);
        }
#pragma unroll
        for (int reg = 0; reg < 4; ++reg) {
            // min over ni: min3 + fmin
            float m = fminf(fminf(fminf(dv[0][reg], dv[1][reg]), dv[2][reg]),
                            dv[3][reg]);
            // 2-level shuffle only; 4 c-group partials folded at store stage
            m = fminf(m, __shfl_xor(m, 1, 64));
            m = fminf(m, __shfl_xor(m, 2, 64));
            if ((c & 3) == 0)
                rmbuf[wc][wr * 64 + mi * 16 + g * 4 + reg][c >> 2] = m;
        }
    }
    // col d^2 mins: reduce across the 4 g-groups
#pragma unroll
    for (int ni = 0; ni < 4; ++ni) {
        float m = colm2[ni];
        m = fminf(m, __shfl_xor(m, 16, 64));
        m = fminf(m, __shfl_xor(m, 32, 64));
        if (g == 0) cmbuf[wr][wc * 64 + ni * 16 + c] = m;
    }
    // grand total: wave reduce
    float tot = (tot4[0] + tot4[1]) + (tot4[2] + tot4[3]);
#pragma unroll
    for (int off = 32; off >= 1; off >>= 1) tot += __shfl_xor(tot, off, 64);
    if (l == 0) tbuf[wid] = tot;
    __syncthreads();

    // plain disjoint stores - no atomics anywhere
    if (tid < 128) {
        f32x4 v0 = *(const f32x4*)rmbuf[0][tid];
        f32x4 v1 = *(const f32x4*)rmbuf[1][tid];
        float m = fminf(fminf(fminf(v0[0], v0[1]), v0[2]), v0[3]);
        m = fminf(fminf(fminf(fminf(m, v1[0]), v1[1]), v1[2]), v1[3]);
        rowpart[(size_t)bx * NN + rowBase + tid] = m;
    } else if (tid < 256) {
        int j = tid - 128;
        colpart[(size_t)by * NN + colBase + j] = fminf(cmbuf[0][j], cmbuf[1][j]);
    }
    if (tid == 0)
        totpart[by * 64 + bx] = tbuf[0] + tbuf[1] + tbuf[2] + tbuf[3];
}

// ---------------- fin: 64-way partial reduce + last-block scalar emit ----------------
__global__ __launch_bounds__(256) void fin_kernel(const float* __restrict__ rowpart,
                                                  const float* __restrict__ colpart,
                                                  const float* __restrict__ totpart,
                                                  float* __restrict__ finpart,
                                                  unsigned int* __restrict__ done,
                                                  float* __restrict__ out) {
    const int idx = blockIdx.x * 256 + threadIdx.x;   // 0..16383
    const int j = (idx < NN) ? idx : idx - NN;
    const float* p = (idx < NN) ? rowpart : colpart;
    float m = BIGF;
#pragma unroll 8
    for (int k = 0; k < 64; ++k) m = fminf(m, p[(size_t)k * NN + j]);
    float contrib = -__builtin_amdgcn_sqrtf(fmaxf(m, 0.f)) * (1.0f / 16384.0f);
    if (blockIdx.x < 16)
        contrib += totpart[blockIdx.x * 256 + threadIdx.x] * (1.0f / 67108864.0f);
#pragma unroll
    for (int off = 32; off >= 1; off >>= 1) contrib += __shfl_xor(contrib, off, 64);
    __shared__ float red[4];
    __shared__ unsigned last;
    if ((threadIdx.x & 63) == 0) red[threadIdx.x >> 6] = contrib;
    __syncthreads();
    if (threadIdx.x == 0) {
        finpart[blockIdx.x] = red[0] + red[1] + red[2] + red[3];
        __threadfence();                       // release finpart
        last = (atomicAdd(done, 1u) == 63u) ? 1u : 0u;
    }
    __syncthreads();
    if (last && threadIdx.x < 64) {
        __threadfence();                       // acquire
        float s = __hip_atomic_load(&finpart[threadIdx.x], __ATOMIC_RELAXED,
                                    __HIP_MEMORY_SCOPE_AGENT);
#pragma unroll
        for (int off = 32; off >= 1; off >>= 1) s += __shfl_xor(s, off, 64);
        if (threadIdx.x == 0) out[0] = s + 1.0f - 1.0f / 8192.0f;
    }
}

extern "C" void kernel_launch(void* const* d_in, const int* in_sizes, int n_in,
                              void* d_out, int out_size, void* d_ws, size_t ws_size,
                              hipStream_t stream) {
    const float* A = (const float*)d_in[0];
    const float* B = (const float*)d_in[1];
    char* ws = (char*)d_ws;

    const size_t MB = 1024 * 1024;
    __hip_bfloat16* Abf = (__hip_bfloat16*)(ws);                  // 2 MB
    __hip_bfloat16* Bbf = (__hip_bfloat16*)(ws + 2 * MB);         // 2 MB
    float* na      = (float*)(ws + 4 * MB);                       // 32 KB
    float* nb      = (float*)(ws + 4 * MB + 32768);               // 32 KB
    float* rowpart = (float*)(ws + 4 * MB + 65536);               // 2 MB  [ct][8192]
    float* colpart = (float*)(ws + 6 * MB + 65536);               // 2 MB  [rt][8192]
    float* totpart = (float*)(ws + 8 * MB + 65536);               // 16 KB
    float* finpart = (float*)(ws + 8 * MB + 65536 + 16384);       // 256 B
    unsigned int* done = (unsigned int*)(ws + 8 * MB + 65536 + 16384 + 256);

    dim3 pgrid(NN / 8, 2);
    prep_kernel<<<pgrid, 256, 0, stream>>>(A, B, Abf, Bbf, na, nb, done);

    dim3 grid(NN / 128, NN / 128);
    dist_fused<<<grid, 256, 0, stream>>>(Abf, Bbf, na, nb, rowpart, colpart, totpart);

    fin_kernel<<<64, 256, 0, stream>>>(rowpart, colpart, totpart, finpart, done,
                                       (float*)d_out);
}